// Round 1
// baseline (257.087 us; speedup 1.0000x reference)
//
#include <hip/hip_runtime.h>
#include <hip/hip_bf16.h>

typedef __bf16 bf16x8 __attribute__((ext_vector_type(8)));
typedef __bf16 bf16x4 __attribute__((ext_vector_type(4)));
typedef float  f32x4  __attribute__((ext_vector_type(4)));

#define MDIM 128   // MSA rows (m)
#define NDIM 256   // residues (i/j)
#define CDIM 256   // channels
#define MIDC 32
#define OUTC 128

// ---------------------------------------------------------------------------
// prep: norm_inv, bf16 weight copies, combined bias
// grid: 328 blocks x 256 threads
//   [0,256): norm_inv row i = blockIdx
//   [256,320): owb conversion (64*2048 = 131072)
//   [320,328): wb = lw||rw bf16 (8*2048 = 16384); block 320 also fills cbias
// ---------------------------------------------------------------------------
__global__ __launch_bounds__(256) void prep_kernel(
    const float* __restrict__ mask,
    const float* __restrict__ lw, const float* __restrict__ lb,
    const float* __restrict__ rw, const float* __restrict__ rb,
    const float* __restrict__ ow,
    __bf16* __restrict__ wb, float* __restrict__ cbias,
    __bf16* __restrict__ owb, float* __restrict__ norm_inv)
{
    int b = blockIdx.x, t = threadIdx.x;
    if (b < 256) {
        float s = 0.f;
        #pragma unroll 4
        for (int m = 0; m < MDIM; ++m)
            s += mask[m*NDIM + b] * mask[m*NDIM + t];
        norm_inv[b*NDIM + t] = 1.0f / (s + 1e-3f);
    } else if (b < 320) {
        int e0 = (b - 256)*2048 + t*8;
        #pragma unroll
        for (int j = 0; j < 8; ++j) owb[e0 + j] = (__bf16)ow[e0 + j];
    } else {
        int e0 = (b - 320)*2048 + t*8;
        #pragma unroll
        for (int j = 0; j < 8; ++j) {
            int e = e0 + j;
            int row = e >> 8, c = e & 255;
            wb[e] = (__bf16)(row < MIDC ? lw[row*CDIM + c] : rw[(row - MIDC)*CDIM + c]);
        }
        if (b == 320 && t < 64) cbias[t] = (t < MIDC) ? lb[t] : rb[t - MIDC];
    }
}

// ---------------------------------------------------------------------------
// ln_proj: LayerNorm 64 rows -> LDS bf16, then MFMA projection to 64 outputs.
// Writes left_t[(i*32+x)][m], right_t[(j*32+y)][m]  (row-major, 128 bf16/row)
// grid: 512 blocks x 256 threads (4 waves; wave w owns rows w*16..w*16+15)
// ---------------------------------------------------------------------------
__global__ __launch_bounds__(256) void ln_proj_kernel(
    const float* __restrict__ act, const float* __restrict__ mask,
    const float* __restrict__ ln_g, const float* __restrict__ ln_b,
    const __bf16* __restrict__ wb, const float* __restrict__ cbias,
    __bf16* __restrict__ left_t, __bf16* __restrict__ right_t)
{
    __shared__ __bf16 xls[64][264];   // pad 264: row stride 528B = 4 banks -> 2-way (free)
    int t = threadIdx.x, lane = t & 63, w = t >> 6;
    int quad = lane >> 4, l16 = lane & 15;
    int r0 = blockIdx.x * 64;
    const float inv_c = 1.0f / 256.0f;

    float4 gv = *(const float4*)(ln_g + lane*4);
    float4 bv = *(const float4*)(ln_b + lane*4);

    for (int s = 0; s < 16; ++s) {
        int p = w*16 + s;
        float4 v = *(const float4*)(act + (size_t)(r0 + p)*CDIM + lane*4);
        float sum = v.x + v.y + v.z + v.w;
        float ssq = v.x*v.x + v.y*v.y + v.z*v.z + v.w*v.w;
        #pragma unroll
        for (int m = 1; m < 64; m <<= 1) {
            sum += __shfl_xor(sum, m);
            ssq += __shfl_xor(ssq, m);
        }
        float mu   = sum * inv_c;
        float var  = ssq * inv_c - mu*mu;
        float rstd = rsqrtf(var + 1e-5f);
        bf16x4 o;
        o.x = (__bf16)((v.x - mu)*rstd*gv.x + bv.x);
        o.y = (__bf16)((v.y - mu)*rstd*gv.y + bv.y);
        o.z = (__bf16)((v.z - mu)*rstd*gv.z + bv.z);
        o.w = (__bf16)((v.w - mu)*rstd*gv.w + bv.w);
        *(bf16x4*)&xls[p][lane*4] = o;
    }
    __syncthreads();

    f32x4 acc[4] = {};
    const __bf16* arow = &xls[w*16 + l16][0];
    #pragma unroll
    for (int k0 = 0; k0 < 256; k0 += 32) {
        bf16x8 a = *(const bf16x8*)(arow + k0 + quad*8);
        #pragma unroll
        for (int tt = 0; tt < 4; ++tt) {
            bf16x8 bb = *(const bf16x8*)(wb + (size_t)(tt*16 + l16)*CDIM + k0 + quad*8);
            acc[tt] = __builtin_amdgcn_mfma_f32_16x16x32_bf16(a, bb, acc[tt], 0, 0, 0);
        }
    }

    // C/D layout: col(o) = lane&15, row(pos) = quad*4 + reg
    #pragma unroll
    for (int tt = 0; tt < 4; ++tt) {
        int o = tt*16 + l16;
        float bias = cbias[o];
        int x = o & 31;
        __bf16* dst = (o < MIDC) ? left_t : right_t;
        #pragma unroll
        for (int rg = 0; rg < 4; ++rg) {
            int pos = r0 + w*16 + quad*4 + rg;
            int mm = pos >> 8, ii = pos & 255;
            float val = mask[mm*NDIM + ii] * (acc[tt][rg] + bias);
            dst[(size_t)(ii*32 + x)*MDIM + mm] = (__bf16)val;
        }
    }
}

// ---------------------------------------------------------------------------
// outer: fused GEMM1 (x2d tile) + GEMM2 (ow projection) + norm epilogue.
// Block = 4x4 (i,j) tile. GEMM1: 128x128x128. GEMM2: 16x128x1024.
// grid: dim3(64,64) x 256 threads
// ---------------------------------------------------------------------------
__global__ __launch_bounds__(256) void outer_kernel(
    const __bf16* __restrict__ left_t, const __bf16* __restrict__ right_t,
    const __bf16* __restrict__ owb, const float* __restrict__ ob,
    const float* __restrict__ norm_inv, float* __restrict__ out)
{
    __shared__ __attribute__((aligned(16))) unsigned char smem[69632];
    __bf16* lsA = (__bf16*)smem;             // [128][136]
    __bf16* lsB = (__bf16*)(smem + 34816);   // [128][136]
    __bf16* lsX = (__bf16*)smem;             // [16][1032] (overlays lsA after barrier)

    int t = threadIdx.x, lane = t & 63, w = t >> 6;
    int quad = lane >> 4, l16 = lane & 15;
    int bi = blockIdx.x, bj = blockIdx.y;

    // stage L/R tiles: contiguous 32 KB each, pad rows to 136 bf16
    const uint4* gA = (const uint4*)(left_t  + (size_t)bi*128*128);
    const uint4* gB = (const uint4*)(right_t + (size_t)bj*128*128);
    #pragma unroll
    for (int q = 0; q < 8; ++q) {
        int idx = t + q*256;          // 0..2047
        int r = idx >> 4, c8 = idx & 15;
        uint4 dA = gA[idx];
        uint4 dB = gB[idx];
        *(uint4*)(lsA + r*136 + c8*8) = dA;
        *(uint4*)(lsB + r*136 + c8*8) = dB;
    }
    __syncthreads();

    // GEMM1: rows (i_l*32+x) x cols (j_l*32+y), K = m (128)
    int wr = w & 1, wc = w >> 1;
    f32x4 acc1[4][4] = {};
    #pragma unroll
    for (int k0 = 0; k0 < 128; k0 += 32) {
        bf16x8 af[4], bf_[4];
        #pragma unroll
        for (int tr = 0; tr < 4; ++tr)
            af[tr] = *(const bf16x8*)(lsA + (size_t)(wr*64 + tr*16 + l16)*136 + k0 + quad*8);
        #pragma unroll
        for (int tc = 0; tc < 4; ++tc)
            bf_[tc] = *(const bf16x8*)(lsB + (size_t)(wc*64 + tc*16 + l16)*136 + k0 + quad*8);
        #pragma unroll
        for (int tr = 0; tr < 4; ++tr)
            #pragma unroll
            for (int tc = 0; tc < 4; ++tc)
                acc1[tr][tc] = __builtin_amdgcn_mfma_f32_16x16x32_bf16(af[tr], bf_[tc], acc1[tr][tc], 0, 0, 0);
    }
    __syncthreads();

    // re-layout (i,x)x(j,y) -> (ij)x(xy) in LDS, bf16
    #pragma unroll
    for (int tr = 0; tr < 4; ++tr) {
        #pragma unroll
        for (int tc = 0; tc < 4; ++tc) {
            int Cc = wc*64 + tc*16 + l16;
            int jl = Cc >> 5, y = Cc & 31;
            #pragma unroll
            for (int rg = 0; rg < 4; ++rg) {
                int R = wr*64 + tr*16 + quad*4 + rg;
                int il = R >> 5, x = R & 31;
                lsX[(size_t)(il*4 + jl)*1032 + x*32 + y] = (__bf16)acc1[tr][tc][rg];
            }
        }
    }
    __syncthreads();

    // GEMM2: [16 ij] x [128 o], K = 1024. Wave w owns o-tiles 2w, 2w+1.
    f32x4 acc2[2] = {};
    for (int k0 = 0; k0 < 1024; k0 += 32) {
        bf16x8 a = *(const bf16x8*)(lsX + (size_t)l16*1032 + k0 + quad*8);
        #pragma unroll
        for (int tt = 0; tt < 2; ++tt) {
            bf16x8 bb = *(const bf16x8*)(owb + (size_t)(w*32 + tt*16 + l16)*1024 + k0 + quad*8);
            acc2[tt] = __builtin_amdgcn_mfma_f32_16x16x32_bf16(a, bb, acc2[tt], 0, 0, 0);
        }
    }

    // epilogue: + ob, * norm_inv, write fp32
    #pragma unroll
    for (int tt = 0; tt < 2; ++tt) {
        int o = w*32 + tt*16 + l16;
        float obv = ob[o];
        #pragma unroll
        for (int rg = 0; rg < 4; ++rg) {
            int ij = quad*4 + rg;
            int il = ij >> 2, jl = ij & 3;
            int i = bi*4 + il, j = bj*4 + jl;
            float v = (acc2[tt][rg] + obv) * norm_inv[i*NDIM + j];
            out[((size_t)(i*NDIM + j))*OUTC + o] = v;
        }
    }
}

// ---------------------------------------------------------------------------
extern "C" void kernel_launch(void* const* d_in, const int* in_sizes, int n_in,
                              void* d_out, int out_size, void* d_ws, size_t ws_size,
                              hipStream_t stream) {
    const float* act  = (const float*)d_in[0];
    const float* mask = (const float*)d_in[1];
    const float* ln_g = (const float*)d_in[2];
    const float* ln_b = (const float*)d_in[3];
    const float* lw   = (const float*)d_in[4];
    const float* lb   = (const float*)d_in[5];
    const float* rw   = (const float*)d_in[6];
    const float* rb   = (const float*)d_in[7];
    const float* ow   = (const float*)d_in[8];
    const float* ob   = (const float*)d_in[9];
    float* out = (float*)d_out;

    // workspace layout (bytes)
    unsigned char* ws = (unsigned char*)d_ws;
    __bf16* left_t   = (__bf16*)(ws + 0);                 // 8192*128*2 = 2 MB
    __bf16* right_t  = (__bf16*)(ws + (2u<<20));          // 2 MB
    __bf16* owb      = (__bf16*)(ws + (4u<<20));          // 128*1024*2 = 256 KB
    float*  norm_inv = (float*) (ws + (4u<<20) + (256u<<10));   // 256 KB
    __bf16* wb       = (__bf16*)(ws + (4u<<20) + (512u<<10));   // 32 KB
    float*  cbias    = (float*) (ws + (4u<<20) + (544u<<10));   // 256 B

    prep_kernel<<<328, 256, 0, stream>>>(mask, lw, lb, rw, rb, ow,
                                         wb, cbias, owb, norm_inv);
    ln_proj_kernel<<<512, 256, 0, stream>>>(act, mask, ln_g, ln_b,
                                            wb, cbias, left_t, right_t);
    outer_kernel<<<dim3(64, 64), 256, 0, stream>>>(left_t, right_t, owb, ob,
                                                   norm_inv, out);
}

// Round 2
// 226.864 us; speedup vs baseline: 1.1332x; 1.1332x over previous
//
#include <hip/hip_runtime.h>
#include <hip/hip_bf16.h>

typedef __bf16 bf16x8 __attribute__((ext_vector_type(8)));
typedef __bf16 bf16x4 __attribute__((ext_vector_type(4)));
typedef float  f32x4  __attribute__((ext_vector_type(4)));

#define MDIM 128   // MSA rows (m)
#define NDIM 256   // residues (i/j)
#define CDIM 256   // channels
#define MIDC 32
#define OUTC 128

#define LSX_RL 1156   // lsX row stride (bf16): 578 dw == 2 mod 32 -> l16 rows spread banks
#define LSX_XS 36     // x-stride (bf16): quad*4*36*2B = 72 dw == 8 mod 32 -> quads tile banks

// ---------------------------------------------------------------------------
// prep: norm_inv, bf16 weight copies, combined bias (unchanged from R1)
// ---------------------------------------------------------------------------
__global__ __launch_bounds__(256) void prep_kernel(
    const float* __restrict__ mask,
    const float* __restrict__ lw, const float* __restrict__ lb,
    const float* __restrict__ rw, const float* __restrict__ rb,
    const float* __restrict__ ow,
    __bf16* __restrict__ wb, float* __restrict__ cbias,
    __bf16* __restrict__ owb, float* __restrict__ norm_inv)
{
    int b = blockIdx.x, t = threadIdx.x;
    if (b < 256) {
        float s = 0.f;
        #pragma unroll 8
        for (int m = 0; m < MDIM; ++m)
            s += mask[m*NDIM + b] * mask[m*NDIM + t];
        norm_inv[b*NDIM + t] = 1.0f / (s + 1e-3f);
    } else if (b < 320) {
        int e0 = (b - 256)*2048 + t*8;
        #pragma unroll
        for (int j = 0; j < 8; ++j) owb[e0 + j] = (__bf16)ow[e0 + j];
    } else {
        int e0 = (b - 320)*2048 + t*8;
        #pragma unroll
        for (int j = 0; j < 8; ++j) {
            int e = e0 + j;
            int row = e >> 8, c = e & 255;
            wb[e] = (__bf16)(row < MIDC ? lw[row*CDIM + c] : rw[(row - MIDC)*CDIM + c]);
        }
        if (b == 320 && t < 64) cbias[t] = (t < MIDC) ? lb[t] : rb[t - MIDC];
    }
}

// ---------------------------------------------------------------------------
// ln_proj v2: block = (column i, m-half). LN 64 rows -> LDS -> MFMA ->
// LDS transpose -> fully coalesced bf16x8 global writes along m.
// grid: dim3(256, 2) x 256 threads (4 waves; wave w owns rows w*16..w*16+15)
// ---------------------------------------------------------------------------
__global__ __launch_bounds__(256) void ln_proj_kernel(
    const float* __restrict__ act, const float* __restrict__ mask,
    const float* __restrict__ ln_g, const float* __restrict__ ln_b,
    const __bf16* __restrict__ wb, const float* __restrict__ cbias,
    __bf16* __restrict__ left_t, __bf16* __restrict__ right_t)
{
    __shared__ __bf16 xls[64][264];   // 33792 B; row 528B = 132 dw == 4 mod 32
    __shared__ __bf16 T[64][72];      // 9216 B; row 144B: 16B-aligned, 36 dw == 4 mod 32
    int t = threadIdx.x, lane = t & 63, w = t >> 6;
    int quad = lane >> 4, l16 = lane & 15;
    int b  = blockIdx.x;      // residue column i
    int m0 = blockIdx.y * 64; // m half

    float4 gv = *(const float4*)(ln_g + lane*4);
    float4 bv = *(const float4*)(ln_b + lane*4);
    const float inv_c = 1.0f / 256.0f;

    #pragma unroll 4
    for (int s = 0; s < 16; ++s) {
        int m = m0 + w*16 + s;
        float4 v = *(const float4*)(act + ((size_t)m*NDIM + b)*CDIM + lane*4);
        float sum = v.x + v.y + v.z + v.w;
        float ssq = v.x*v.x + v.y*v.y + v.z*v.z + v.w*v.w;
        #pragma unroll
        for (int d = 1; d < 64; d <<= 1) {
            sum += __shfl_xor(sum, d);
            ssq += __shfl_xor(ssq, d);
        }
        float mu   = sum * inv_c;
        float var  = ssq * inv_c - mu*mu;
        float rstd = rsqrtf(var + 1e-5f);
        bf16x4 o;
        o.x = (__bf16)((v.x - mu)*rstd*gv.x + bv.x);
        o.y = (__bf16)((v.y - mu)*rstd*gv.y + bv.y);
        o.z = (__bf16)((v.z - mu)*rstd*gv.z + bv.z);
        o.w = (__bf16)((v.w - mu)*rstd*gv.w + bv.w);
        *(bf16x4*)&xls[w*16 + s][lane*4] = o;
    }
    // wave-local rows: no barrier needed (compiler emits lgkmcnt waits)

    f32x4 acc[4] = {};
    const __bf16* arow = &xls[w*16 + l16][0];
    #pragma unroll
    for (int k0 = 0; k0 < 256; k0 += 32) {
        bf16x8 a = *(const bf16x8*)(arow + k0 + quad*8);
        #pragma unroll
        for (int tt = 0; tt < 4; ++tt) {
            bf16x8 bb = *(const bf16x8*)(wb + (size_t)(tt*16 + l16)*CDIM + k0 + quad*8);
            acc[tt] = __builtin_amdgcn_mfma_f32_16x16x32_bf16(a, bb, acc[tt], 0, 0, 0);
        }
    }

    // epilogue: mask + bias, transpose through T (C row = m-pos, col = o)
    #pragma unroll
    for (int rg = 0; rg < 4; ++rg) {
        int ml = w*16 + quad*4 + rg;
        float mval = mask[(size_t)(m0 + ml)*NDIM + b];
        #pragma unroll
        for (int tt = 0; tt < 4; ++tt) {
            int o = tt*16 + l16;
            T[o][ml] = (__bf16)(mval * (acc[tt][rg] + cbias[o]));
        }
    }
    __syncthreads();

    // coalesced writeback: thread t -> output row o=t>>2, m-chunk (t&3)*16
    int o = t >> 2, ch = t & 3;
    bf16x8 d0 = *(const bf16x8*)&T[o][ch*16];
    bf16x8 d1 = *(const bf16x8*)&T[o][ch*16 + 8];
    __bf16* dst = (o < MIDC)
        ? left_t  + ((size_t)b*MIDC + o)*MDIM
        : right_t + ((size_t)b*MIDC + (o - MIDC))*MDIM;
    *(bf16x8*)(dst + m0 + ch*16)     = d0;
    *(bf16x8*)(dst + m0 + ch*16 + 8) = d1;
}

// ---------------------------------------------------------------------------
// outer v2: 4i x 8j tile per block, 512 threads (8 waves, 2x4 wave grid).
// GEMM1 (128x256x128) fragments straight from L2 (left_t/right_t are already
// in A/B-fragment layout). Single barrier. GEMM2 (32x128x1024) with 2x owb
// fragment reuse. lsX swizzle-padded: x-stride 36, row stride 1156.
// grid: dim3(64, 32) x 512
// ---------------------------------------------------------------------------
__global__ __launch_bounds__(512, 4) void outer_kernel(
    const __bf16* __restrict__ left_t, const __bf16* __restrict__ right_t,
    const __bf16* __restrict__ owb, const float* __restrict__ ob,
    const float* __restrict__ norm_inv, float* __restrict__ out)
{
    extern __shared__ __bf16 lsX[];   // 32 * 1156 * 2 = 73984 B
    int t = threadIdx.x, lane = t & 63, w = t >> 6;   // w 0..7
    int quad = lane >> 4, l16 = lane & 15;
    int wr = w & 1, wc = w >> 1;
    int bi = blockIdx.x, bj = blockIdx.y;

    const __bf16* Ab = left_t  + ((size_t)(bi*128 + wr*64 + l16))*MDIM + quad*8;
    const __bf16* Bb = right_t + ((size_t)(bj*256 + wc*64 + l16))*MDIM + quad*8;

    // GEMM1: K = m = 128
    f32x4 acc1[4][4] = {};
    #pragma unroll
    for (int k0 = 0; k0 < 128; k0 += 32) {
        bf16x8 af[4], bg[4];
        #pragma unroll
        for (int tr = 0; tr < 4; ++tr) af[tr] = *(const bf16x8*)(Ab + tr*16*MDIM + k0);
        #pragma unroll
        for (int tc = 0; tc < 4; ++tc) bg[tc] = *(const bf16x8*)(Bb + tc*16*MDIM + k0);
        #pragma unroll
        for (int tr = 0; tr < 4; ++tr)
            #pragma unroll
            for (int tc = 0; tc < 4; ++tc)
                acc1[tr][tc] = __builtin_amdgcn_mfma_f32_16x16x32_bf16(af[tr], bg[tc], acc1[tr][tc], 0, 0, 0);
    }

    // relayout (i,x)x(j,y) -> lsX[ij][x*36 + y]
    #pragma unroll
    for (int tr = 0; tr < 4; ++tr) {
        int R0 = wr*64 + tr*16 + quad*4;
        #pragma unroll
        for (int tc = 0; tc < 4; ++tc) {
            int Cc = wc*64 + tc*16 + l16;
            int jl = Cc >> 5, y = Cc & 31;
            #pragma unroll
            for (int rg = 0; rg < 4; ++rg) {
                int R = R0 + rg, il = R >> 5, x = R & 31;
                lsX[(il*8 + jl)*LSX_RL + x*LSX_XS + y] = (__bf16)acc1[tr][tc][rg];
            }
        }
    }
    __syncthreads();

    // GEMM2: rows = 32 ij (2 m-tiles), cols: wave w owns o = w*16 + l16
    f32x4 acc2[2] = {};
    const __bf16* Ob  = owb + ((size_t)(w*16 + l16))*1024 + quad*8;
    const __bf16* Xb0 = lsX + l16*LSX_RL + quad*8;
    #pragma unroll 4
    for (int k0 = 0; k0 < 1024; k0 += 32) {
        int x = k0 >> 5;
        bf16x8 bb = *(const bf16x8*)(Ob + k0);
        #pragma unroll
        for (int mt = 0; mt < 2; ++mt) {
            const __bf16* ap = Xb0 + mt*16*LSX_RL + x*LSX_XS;
            bf16x4 lo = *(const bf16x4*)(ap);
            bf16x4 hi = *(const bf16x4*)(ap + 4);
            bf16x8 a  = __builtin_shufflevector(lo, hi, 0, 1, 2, 3, 4, 5, 6, 7);
            acc2[mt] = __builtin_amdgcn_mfma_f32_16x16x32_bf16(a, bb, acc2[mt], 0, 0, 0);
        }
    }

    // epilogue: + ob, * norm_inv, write fp32
    int o = w*16 + l16;
    float obv = ob[o];
    #pragma unroll
    for (int mt = 0; mt < 2; ++mt) {
        #pragma unroll
        for (int rg = 0; rg < 4; ++rg) {
            int ij = mt*16 + quad*4 + rg;
            int i = bi*4 + (ij >> 3), j = bj*8 + (ij & 7);
            float v = (acc2[mt][rg] + obv) * norm_inv[i*NDIM + j];
            out[((size_t)(i*NDIM + j))*OUTC + o] = v;
        }
    }
}

// ---------------------------------------------------------------------------
extern "C" void kernel_launch(void* const* d_in, const int* in_sizes, int n_in,
                              void* d_out, int out_size, void* d_ws, size_t ws_size,
                              hipStream_t stream) {
    const float* act  = (const float*)d_in[0];
    const float* mask = (const float*)d_in[1];
    const float* ln_g = (const float*)d_in[2];
    const float* ln_b = (const float*)d_in[3];
    const float* lw   = (const float*)d_in[4];
    const float* lb   = (const float*)d_in[5];
    const float* rw   = (const float*)d_in[6];
    const float* rb   = (const float*)d_in[7];
    const float* ow   = (const float*)d_in[8];
    const float* ob   = (const float*)d_in[9];
    float* out = (float*)d_out;

    unsigned char* ws = (unsigned char*)d_ws;
    __bf16* left_t   = (__bf16*)(ws + 0);                 // 8192*128*2 = 2 MB
    __bf16* right_t  = (__bf16*)(ws + (2u<<20));          // 2 MB
    __bf16* owb      = (__bf16*)(ws + (4u<<20));          // 256 KB
    float*  norm_inv = (float*) (ws + (4u<<20) + (256u<<10));   // 256 KB
    __bf16* wb       = (__bf16*)(ws + (4u<<20) + (512u<<10));   // 32 KB
    float*  cbias    = (float*) (ws + (4u<<20) + (544u<<10));   // 256 B

    // opt-in to >64KB dynamic LDS for outer_kernel (idempotent, graph-safe)
    hipFuncSetAttribute((const void*)outer_kernel,
                        hipFuncAttributeMaxDynamicSharedMemorySize, 32*LSX_RL*2);

    prep_kernel<<<328, 256, 0, stream>>>(mask, lw, lb, rw, rb, ow,
                                         wb, cbias, owb, norm_inv);
    ln_proj_kernel<<<dim3(256, 2), 256, 0, stream>>>(act, mask, ln_g, ln_b,
                                                     wb, cbias, left_t, right_t);
    outer_kernel<<<dim3(64, 32), 512, 32*LSX_RL*2, stream>>>(left_t, right_t, owb, ob,
                                                             norm_inv, out);
}

// Round 3
// 207.256 us; speedup vs baseline: 1.2404x; 1.0946x over previous
//
#include <hip/hip_runtime.h>
#include <hip/hip_bf16.h>

typedef __bf16 bf16x8 __attribute__((ext_vector_type(8)));
typedef __bf16 bf16x4 __attribute__((ext_vector_type(4)));
typedef float  f32x4  __attribute__((ext_vector_type(4)));

#define MDIM 128   // MSA rows (m)
#define NDIM 256   // residues (i/j)
#define CDIM 256   // channels
#define MIDC 32
#define OUTC 128

#define LSX_RS 1156   // lsX row stride (bf16): 578 dw == 2 mod 32
#define LSX_XS 36     // x-stride (bf16): spreads quads across banks (R2: 0 conflicts)
#define LSX_BYTES (64 * LSX_RS * 2)   // 147968 B

// ---------------------------------------------------------------------------
// prep: norm_inv, bf16 weight copies, combined bias
// ---------------------------------------------------------------------------
__global__ __launch_bounds__(256) void prep_kernel(
    const float* __restrict__ mask,
    const float* __restrict__ lw, const float* __restrict__ lb,
    const float* __restrict__ rw, const float* __restrict__ rb,
    const float* __restrict__ ow,
    __bf16* __restrict__ wb, float* __restrict__ cbias,
    __bf16* __restrict__ owb, float* __restrict__ norm_inv)
{
    int b = blockIdx.x, t = threadIdx.x;
    if (b < 256) {
        float s = 0.f;
        #pragma unroll 8
        for (int m = 0; m < MDIM; ++m)
            s += mask[m*NDIM + b] * mask[m*NDIM + t];
        norm_inv[b*NDIM + t] = 1.0f / (s + 1e-3f);
    } else if (b < 320) {
        int e0 = (b - 256)*2048 + t*8;
        #pragma unroll
        for (int j = 0; j < 8; ++j) owb[e0 + j] = (__bf16)ow[e0 + j];
    } else {
        int e0 = (b - 320)*2048 + t*8;
        #pragma unroll
        for (int j = 0; j < 8; ++j) {
            int e = e0 + j;
            int row = e >> 8, c = e & 255;
            wb[e] = (__bf16)(row < MIDC ? lw[row*CDIM + c] : rw[(row - MIDC)*CDIM + c]);
        }
        if (b == 320 && t < 64) cbias[t] = (t < MIDC) ? lb[t] : rb[t - MIDC];
    }
}

// ---------------------------------------------------------------------------
// ln_proj: unchanged from R2 (LN -> MFMA projection -> coalesced transpose)
// grid: dim3(256, 2) x 256
// ---------------------------------------------------------------------------
__global__ __launch_bounds__(256) void ln_proj_kernel(
    const float* __restrict__ act, const float* __restrict__ mask,
    const float* __restrict__ ln_g, const float* __restrict__ ln_b,
    const __bf16* __restrict__ wb, const float* __restrict__ cbias,
    __bf16* __restrict__ left_t, __bf16* __restrict__ right_t)
{
    __shared__ __bf16 xls[64][264];
    __shared__ __bf16 T[64][72];
    int t = threadIdx.x, lane = t & 63, w = t >> 6;
    int quad = lane >> 4, l16 = lane & 15;
    int b  = blockIdx.x;
    int m0 = blockIdx.y * 64;

    float4 gv = *(const float4*)(ln_g + lane*4);
    float4 bv = *(const float4*)(ln_b + lane*4);
    const float inv_c = 1.0f / 256.0f;

    #pragma unroll 4
    for (int s = 0; s < 16; ++s) {
        int m = m0 + w*16 + s;
        float4 v = *(const float4*)(act + ((size_t)m*NDIM + b)*CDIM + lane*4);
        float sum = v.x + v.y + v.z + v.w;
        float ssq = v.x*v.x + v.y*v.y + v.z*v.z + v.w*v.w;
        #pragma unroll
        for (int d = 1; d < 64; d <<= 1) {
            sum += __shfl_xor(sum, d);
            ssq += __shfl_xor(ssq, d);
        }
        float mu   = sum * inv_c;
        float var  = ssq * inv_c - mu*mu;
        float rstd = rsqrtf(var + 1e-5f);
        bf16x4 o;
        o.x = (__bf16)((v.x - mu)*rstd*gv.x + bv.x);
        o.y = (__bf16)((v.y - mu)*rstd*gv.y + bv.y);
        o.z = (__bf16)((v.z - mu)*rstd*gv.z + bv.z);
        o.w = (__bf16)((v.w - mu)*rstd*gv.w + bv.w);
        *(bf16x4*)&xls[w*16 + s][lane*4] = o;
    }

    f32x4 acc[4] = {};
    const __bf16* arow = &xls[w*16 + l16][0];
    #pragma unroll
    for (int k0 = 0; k0 < 256; k0 += 32) {
        bf16x8 a = *(const bf16x8*)(arow + k0 + quad*8);
        #pragma unroll
        for (int tt = 0; tt < 4; ++tt) {
            bf16x8 bb = *(const bf16x8*)(wb + (size_t)(tt*16 + l16)*CDIM + k0 + quad*8);
            acc[tt] = __builtin_amdgcn_mfma_f32_16x16x32_bf16(a, bb, acc[tt], 0, 0, 0);
        }
    }

    #pragma unroll
    for (int rg = 0; rg < 4; ++rg) {
        int ml = w*16 + quad*4 + rg;
        float mval = mask[(size_t)(m0 + ml)*NDIM + b];
        #pragma unroll
        for (int tt = 0; tt < 4; ++tt) {
            int o = tt*16 + l16;
            T[o][ml] = (__bf16)(mval * (acc[tt][rg] + cbias[o]));
        }
    }
    __syncthreads();

    int o = t >> 2, ch = t & 3;
    bf16x8 d0 = *(const bf16x8*)&T[o][ch*16];
    bf16x8 d1 = *(const bf16x8*)&T[o][ch*16 + 8];
    __bf16* dst = (o < MIDC)
        ? left_t  + ((size_t)b*MIDC + o)*MDIM
        : right_t + ((size_t)b*MIDC + (o - MIDC))*MDIM;
    *(bf16x8*)(dst + m0 + ch*16)     = d0;
    *(bf16x8*)(dst + m0 + ch*16 + 8) = d1;
}

// ---------------------------------------------------------------------------
// outer v3: 8i x 8j tile (64 ij rows), 1024 threads (16 waves).
// GEMM1: 256x256x128, wave grid 4x4 (64x64 tiles), frags direct from L2.
// Relayout -> lsX[64][LSX_RS] (144.5 KB, 1 block/CU).
// GEMM2: 16 waves = 8 o-tiles x 2 K-halves (owb read EXACTLY once/block),
//        LDS tree-reduce of the two K-halves, fused bias+norm epilogue.
// Grid: 1024 linear blocks, XCD-swizzled: xcd gets a 4-wide bi strip so the
// per-XCD L2 working set (~2.5 MB) fits in 4 MiB.
// ---------------------------------------------------------------------------
__global__ __launch_bounds__(1024, 4) void outer_kernel(
    const __bf16* __restrict__ left_t, const __bf16* __restrict__ right_t,
    const __bf16* __restrict__ owb, const float* __restrict__ ob,
    const float* __restrict__ norm_inv, float* __restrict__ out)
{
    extern __shared__ __bf16 lsX[];   // 64 * LSX_RS * 2 = 147968 B
    int t = threadIdx.x, lane = t & 63, w = t >> 6;   // w 0..15
    int quad = lane >> 4, l16 = lane & 15;

    // XCD swizzle: linear id -> (bi, bj); xcd x owns bi strip [4x, 4x+4)
    int id = blockIdx.x;
    int xcd = id & 7, p = id >> 3;
    int bi = xcd*4 + (p & 3);
    int bj = p >> 2;

    // ---- GEMM1: 256x256x128, wave (wr, wc) owns 64x64 ----
    int wr = w & 3, wc = w >> 2;
    const __bf16* Ab = left_t  + ((size_t)(bi*256 + wr*64 + l16))*MDIM + quad*8;
    const __bf16* Bb = right_t + ((size_t)(bj*256 + wc*64 + l16))*MDIM + quad*8;

    f32x4 acc1[4][4] = {};
    #pragma unroll
    for (int k0 = 0; k0 < 128; k0 += 32) {
        bf16x8 af[4], bg[4];
        #pragma unroll
        for (int tr = 0; tr < 4; ++tr) af[tr] = *(const bf16x8*)(Ab + tr*16*MDIM + k0);
        #pragma unroll
        for (int tc = 0; tc < 4; ++tc) bg[tc] = *(const bf16x8*)(Bb + tc*16*MDIM + k0);
        #pragma unroll
        for (int tr = 0; tr < 4; ++tr)
            #pragma unroll
            for (int tc = 0; tc < 4; ++tc)
                acc1[tr][tc] = __builtin_amdgcn_mfma_f32_16x16x32_bf16(af[tr], bg[tc], acc1[tr][tc], 0, 0, 0);
    }

    // ---- relayout (i,x)x(j,y) -> lsX[il*8+jl][x*XS + y] ----
    #pragma unroll
    for (int tr = 0; tr < 4; ++tr) {
        int R0 = wr*64 + tr*16 + quad*4;
        #pragma unroll
        for (int tc = 0; tc < 4; ++tc) {
            int Cc = wc*64 + tc*16 + l16;
            int jl = Cc >> 5, y = Cc & 31;
            #pragma unroll
            for (int rg = 0; rg < 4; ++rg) {
                int R = R0 + rg, il = R >> 5, x = R & 31;
                lsX[(il*8 + jl)*LSX_RS + x*LSX_XS + y] = (__bf16)acc1[tr][tc][rg];
            }
        }
    }
    __syncthreads();

    // ---- GEMM2: wave = (o-tile ot, K-half kh). K=512 per wave. ----
    int ot = w & 7, kh = w >> 3;
    f32x4 acc2[4] = {};
    const __bf16* Ob = owb + (size_t)(ot*16 + l16)*1024 + kh*512 + quad*8;
    const __bf16* Xb = lsX + (size_t)l16*LSX_RS + kh*16*LSX_XS + quad*8;
    #pragma unroll 4
    for (int ks = 0; ks < 16; ++ks) {
        bf16x8 bb = *(const bf16x8*)(Ob + ks*32);
        #pragma unroll
        for (int mt = 0; mt < 4; ++mt) {
            const __bf16* ap = Xb + mt*16*LSX_RS + ks*LSX_XS;
            bf16x4 lo = *(const bf16x4*)(ap);
            bf16x4 hi = *(const bf16x4*)(ap + 4);
            bf16x8 a  = __builtin_shufflevector(lo, hi, 0, 1, 2, 3, 4, 5, 6, 7);
            acc2[mt] = __builtin_amdgcn_mfma_f32_16x16x32_bf16(a, bb, acc2[mt], 0, 0, 0);
        }
    }

    // ---- reduce K-halves via LDS scratch (overlays lsX) ----
    __syncthreads();   // all lsX reads complete
    f32x4* red = (f32x4*)lsX;   // 8 waves x 64 lanes x 4 = 32 KB
    if (w >= 8) {
        int base = ((w - 8)*64 + lane)*4;
        #pragma unroll
        for (int mt = 0; mt < 4; ++mt) red[base + mt] = acc2[mt];
    }
    __syncthreads();
    if (w < 8) {
        int base = (w*64 + lane)*4;
        #pragma unroll
        for (int mt = 0; mt < 4; ++mt) acc2[mt] += red[base + mt];

        // ---- epilogue: + ob, * norm_inv, fp32 out ----
        int o = w*16 + l16;
        float obv = ob[o];
        #pragma unroll
        for (int mt = 0; mt < 4; ++mt) {
            #pragma unroll
            for (int rg = 0; rg < 4; ++rg) {
                int ij = mt*16 + quad*4 + rg;
                int i = bi*8 + (ij >> 3), j = bj*8 + (ij & 7);
                float v = (acc2[mt][rg] + obv) * norm_inv[i*NDIM + j];
                out[((size_t)(i*NDIM + j))*OUTC + o] = v;
            }
        }
    }
}

// ---------------------------------------------------------------------------
extern "C" void kernel_launch(void* const* d_in, const int* in_sizes, int n_in,
                              void* d_out, int out_size, void* d_ws, size_t ws_size,
                              hipStream_t stream) {
    const float* act  = (const float*)d_in[0];
    const float* mask = (const float*)d_in[1];
    const float* ln_g = (const float*)d_in[2];
    const float* ln_b = (const float*)d_in[3];
    const float* lw   = (const float*)d_in[4];
    const float* lb   = (const float*)d_in[5];
    const float* rw   = (const float*)d_in[6];
    const float* rb   = (const float*)d_in[7];
    const float* ow   = (const float*)d_in[8];
    const float* ob   = (const float*)d_in[9];
    float* out = (float*)d_out;

    unsigned char* ws = (unsigned char*)d_ws;
    __bf16* left_t   = (__bf16*)(ws + 0);                 // 2 MB
    __bf16* right_t  = (__bf16*)(ws + (2u<<20));          // 2 MB
    __bf16* owb      = (__bf16*)(ws + (4u<<20));          // 256 KB
    float*  norm_inv = (float*) (ws + (4u<<20) + (256u<<10));   // 256 KB
    __bf16* wb       = (__bf16*)(ws + (4u<<20) + (512u<<10));   // 32 KB
    float*  cbias    = (float*) (ws + (4u<<20) + (544u<<10));   // 256 B

    hipFuncSetAttribute((const void*)outer_kernel,
                        hipFuncAttributeMaxDynamicSharedMemorySize, LSX_BYTES);

    prep_kernel<<<328, 256, 0, stream>>>(mask, lw, lb, rw, rb, ow,
                                         wb, cbias, owb, norm_inv);
    ln_proj_kernel<<<dim3(256, 2), 256, 0, stream>>>(act, mask, ln_g, ln_b,
                                                     wb, cbias, left_t, right_t);
    outer_kernel<<<1024, 1024, LSX_BYTES, stream>>>(left_t, right_t, owb, ob,
                                                    norm_inv, out);
}

// Round 4
// 158.452 us; speedup vs baseline: 1.6225x; 1.3080x over previous
//
#include <hip/hip_runtime.h>
#include <hip/hip_bf16.h>

typedef __bf16 bf16x8 __attribute__((ext_vector_type(8)));
typedef __bf16 bf16x4 __attribute__((ext_vector_type(4)));
typedef float  f32x4  __attribute__((ext_vector_type(4)));

#define MDIM 128   // MSA rows (m)
#define NDIM 256   // residues (i/j)
#define CDIM 256   // channels
#define MIDC 32
#define OUTC 128

// lsX: [64 ij][y*36 + x]  (y,x in 0..31), row stride 1156 bf16.
// RS/2 = 578 dw == 2 mod 32 -> GEMM2 b64 reads tile banks perfectly (R2: 0 conf).
// Relayout writes: row uniform per instr, lane dw stride 18 -> perfect tiling.
#define LSX_RS 1156
#define LSX_YS 36
#define LSX_BYTES (64 * LSX_RS * 2)   // 147968 B

// ---------------------------------------------------------------------------
// prep: norm_inv, fragment-linear owb_f, wb (lw||rw bf16), combined bias.
// owb_f[((ot*32+ks)*64 + lane)*8 + j] = ow[ot*16+(lane&15)][((lane>>4)*8+j)*32+ks]
//   (GEMM2 k' = y*32 + x with ks = y, x = (lane>>4)*8+j)
// ---------------------------------------------------------------------------
__global__ __launch_bounds__(256) void prep_kernel(
    const float* __restrict__ mask,
    const float* __restrict__ lw, const float* __restrict__ lb,
    const float* __restrict__ rw, const float* __restrict__ rb,
    const float* __restrict__ ow,
    __bf16* __restrict__ wb, float* __restrict__ cbias,
    __bf16* __restrict__ owb_f, float* __restrict__ norm_inv)
{
    int b = blockIdx.x, t = threadIdx.x;
    if (b < 256) {
        float s = 0.f;
        #pragma unroll 8
        for (int m = 0; m < MDIM; ++m)
            s += mask[m*NDIM + b] * mask[m*NDIM + t];
        norm_inv[b*NDIM + t] = 1.0f / (s + 1e-3f);
    } else if (b < 320) {
        int e0 = (b - 256)*2048 + t*8;
        #pragma unroll
        for (int j = 0; j < 8; ++j) {
            int e = e0 + j;
            int idx = e >> 3, jj = e & 7;
            int lane = idx & 63, tk = idx >> 6;
            int ks = tk & 31, ot = tk >> 5;
            int o = ot*16 + (lane & 15);
            int k = ((lane >> 4)*8 + jj)*32 + ks;
            owb_f[e] = (__bf16)ow[o*1024 + k];
        }
    } else {
        int e0 = (b - 320)*2048 + t*8;
        #pragma unroll
        for (int j = 0; j < 8; ++j) {
            int e = e0 + j;
            int row = e >> 8, c = e & 255;
            wb[e] = (__bf16)(row < MIDC ? lw[row*CDIM + c] : rw[(row - MIDC)*CDIM + c]);
        }
        if (b == 320 && t < 64) cbias[t] = (t < MIDC) ? lb[t] : rb[t - MIDC];
    }
}

// ---------------------------------------------------------------------------
// ln_proj: LN -> MFMA projection -> transpose T -> FRAGMENT-LINEAR writeback.
// left_f/right_f[((tile*4 + k0)*64 + lane)*8 + j]:
//   tile = (i*32+x)>>4, l16 = x&15, k-chunk (lane>>4)*8+j over m within k0.
// grid: dim3(256, 2) x 256
// ---------------------------------------------------------------------------
__global__ __launch_bounds__(256) void ln_proj_kernel(
    const float* __restrict__ act, const float* __restrict__ mask,
    const float* __restrict__ ln_g, const float* __restrict__ ln_b,
    const __bf16* __restrict__ wb, const float* __restrict__ cbias,
    __bf16* __restrict__ left_f, __bf16* __restrict__ right_f)
{
    __shared__ __bf16 xls[64][264];
    __shared__ __bf16 T[64][72];   // [o][m-local]; row 144B, 16B-aligned
    int t = threadIdx.x, lane = t & 63, w = t >> 6;
    int quad = lane >> 4, l16 = lane & 15;
    int b  = blockIdx.x;
    int m0 = blockIdx.y * 64;

    float4 gv = *(const float4*)(ln_g + lane*4);
    float4 bv = *(const float4*)(ln_b + lane*4);
    const float inv_c = 1.0f / 256.0f;

    #pragma unroll 4
    for (int s = 0; s < 16; ++s) {
        int m = m0 + w*16 + s;
        float4 v = *(const float4*)(act + ((size_t)m*NDIM + b)*CDIM + lane*4);
        float sum = v.x + v.y + v.z + v.w;
        float ssq = v.x*v.x + v.y*v.y + v.z*v.z + v.w*v.w;
        #pragma unroll
        for (int d = 1; d < 64; d <<= 1) {
            sum += __shfl_xor(sum, d);
            ssq += __shfl_xor(ssq, d);
        }
        float mu   = sum * inv_c;
        float var  = ssq * inv_c - mu*mu;
        float rstd = rsqrtf(var + 1e-5f);
        bf16x4 o;
        o.x = (__bf16)((v.x - mu)*rstd*gv.x + bv.x);
        o.y = (__bf16)((v.y - mu)*rstd*gv.y + bv.y);
        o.z = (__bf16)((v.z - mu)*rstd*gv.z + bv.z);
        o.w = (__bf16)((v.w - mu)*rstd*gv.w + bv.w);
        *(bf16x4*)&xls[w*16 + s][lane*4] = o;
    }

    f32x4 acc[4] = {};
    const __bf16* arow = &xls[w*16 + l16][0];
    #pragma unroll
    for (int k0 = 0; k0 < 256; k0 += 32) {
        bf16x8 a = *(const bf16x8*)(arow + k0 + quad*8);
        #pragma unroll
        for (int tt = 0; tt < 4; ++tt) {
            bf16x8 bb = *(const bf16x8*)(wb + (size_t)(tt*16 + l16)*CDIM + k0 + quad*8);
            acc[tt] = __builtin_amdgcn_mfma_f32_16x16x32_bf16(a, bb, acc[tt], 0, 0, 0);
        }
    }

    #pragma unroll
    for (int rg = 0; rg < 4; ++rg) {
        int ml = w*16 + quad*4 + rg;
        float mval = mask[(size_t)(m0 + ml)*NDIM + b];
        #pragma unroll
        for (int tt = 0; tt < 4; ++tt) {
            int o = tt*16 + l16;
            T[o][ml] = (__bf16)(mval * (acc[tt][rg] + cbias[o]));
        }
    }
    __syncthreads();

    // fragment-linear writeback: thread t -> (l16, q, k0loc, half); side 0 then 1
    {
        int fl16  = t & 15;
        int r     = t >> 4;
        int q     = r & 3;
        int k0loc = (r >> 2) & 1;
        int half  = (r >> 3) & 1;
        int tile  = b*2 + half;
        int k0    = (m0 >> 5) + k0loc;
        size_t dstoff = (((size_t)tile*4 + k0)*64 + q*16 + fl16)*8;
        #pragma unroll
        for (int side = 0; side < 2; ++side) {
            int o = side*32 + half*16 + fl16;
            bf16x8 d = *(const bf16x8*)&T[o][k0loc*32 + q*8];
            __bf16* dst = side ? right_f : left_f;
            *(bf16x8*)(dst + dstoff) = d;
        }
    }
}

// ---------------------------------------------------------------------------
// outer v4: 8i x 8j (64 ij), 1024 threads / 16 waves, 1 barrier.
// GEMM1: 256x256x128, wave(wr,wc) 4x4 grid, dense fragment-linear loads.
// Relayout: acc quad-packed ds_write_b64 into lsX[ij][y*36+x] (k' = y*32+x).
// GEMM2: wave = (ot 0..7, rt 0..1): o-tile 16, rows rt*32..+32, full K=1024;
//        owb_f dense 1KB loads, prefetch depth 2 issued before the barrier.
// grid: 1024 blocks (XCD-swizzled: xcd owns a 4-wide bi strip)
// ---------------------------------------------------------------------------
__global__ __launch_bounds__(1024, 1) void outer_kernel(
    const __bf16* __restrict__ left_f, const __bf16* __restrict__ right_f,
    const __bf16* __restrict__ owb_f, const float* __restrict__ ob,
    const float* __restrict__ norm_inv, float* __restrict__ out)
{
    extern __shared__ __bf16 lsX[];
    int t = threadIdx.x, lane = t & 63, w = t >> 6;   // w 0..15
    int quad = lane >> 4, l16 = lane & 15;

    int id = blockIdx.x;
    int xcd = id & 7, p = id >> 3;
    int bi = xcd*4 + (p & 3);
    int bj = p >> 2;

    // ---- GEMM1: 256x256x128, wave (wr,wc) owns 64x64 ----
    int wr = w & 3, wc = w >> 2;
    const __bf16* Af = left_f  + ((size_t)(bi*16 + wr*4)*4)*512 + lane*8;
    const __bf16* Bf = right_f + ((size_t)(bj*16 + wc*4)*4)*512 + lane*8;

    f32x4 acc1[4][4] = {};
    #pragma unroll
    for (int kk = 0; kk < 4; ++kk) {          // k0 = kk*32
        bf16x8 af[4], bg[4];
        #pragma unroll
        for (int tr = 0; tr < 4; ++tr) af[tr] = *(const bf16x8*)(Af + tr*2048 + kk*512);
        #pragma unroll
        for (int tc = 0; tc < 4; ++tc) bg[tc] = *(const bf16x8*)(Bf + tc*2048 + kk*512);
        #pragma unroll
        for (int tr = 0; tr < 4; ++tr)
            #pragma unroll
            for (int tc = 0; tc < 4; ++tc)
                acc1[tr][tc] = __builtin_amdgcn_mfma_f32_16x16x32_bf16(af[tr], bg[tc], acc1[tr][tc], 0, 0, 0);
    }

    // ---- GEMM2 setup + owb prefetch (before barrier: overlaps relayout) ----
    int ot = w & 7, rt = w >> 3;
    const __bf16* Ob = owb_f + ((size_t)(ot*32)*64 + lane)*8;   // +ks*512
    bf16x8 bbuf0 = *(const bf16x8*)(Ob);
    bf16x8 bbuf1 = *(const bf16x8*)(Ob + 512);

    // ---- relayout: (i,x)x(j,y) -> lsX[il*8+jl][y*36 + x], b64 writes ----
    #pragma unroll
    for (int tr = 0; tr < 4; ++tr) {
        int il = wr*2 + (tr >> 1);
        int x0 = (tr & 1)*16 + quad*4;
        #pragma unroll
        for (int tc = 0; tc < 4; ++tc) {
            int jl = wc*2 + (tc >> 1);
            int y  = (tc & 1)*16 + l16;
            bf16x4 pk;
            pk.x = (__bf16)acc1[tr][tc][0];
            pk.y = (__bf16)acc1[tr][tc][1];
            pk.z = (__bf16)acc1[tr][tc][2];
            pk.w = (__bf16)acc1[tr][tc][3];
            *(bf16x4*)(lsX + (size_t)(il*8 + jl)*LSX_RS + y*LSX_YS + x0) = pk;
        }
    }
    __syncthreads();

    // ---- GEMM2: full K=1024 per wave, rows rt*32 + {0,16} ----
    f32x4 acc2[2] = {};
    const __bf16* Xb = lsX + (size_t)(rt*32 + l16)*LSX_RS + quad*8;
    #pragma unroll
    for (int ks = 0; ks < 32; ++ks) {
        bf16x8 bb = bbuf0;
        bbuf0 = bbuf1;
        if (ks + 2 < 32) bbuf1 = *(const bf16x8*)(Ob + (ks + 2)*512);
        #pragma unroll
        for (int mt = 0; mt < 2; ++mt) {
            const __bf16* ap = Xb + mt*16*LSX_RS + ks*LSX_YS;
            bf16x4 lo = *(const bf16x4*)(ap);
            bf16x4 hi = *(const bf16x4*)(ap + 4);
            bf16x8 a  = __builtin_shufflevector(lo, hi, 0, 1, 2, 3, 4, 5, 6, 7);
            acc2[mt] = __builtin_amdgcn_mfma_f32_16x16x32_bf16(a, bb, acc2[mt], 0, 0, 0);
        }
    }

    // ---- epilogue: + ob, * norm_inv, fp32 out (all 16 waves) ----
    int o = ot*16 + l16;
    float obv = ob[o];
    #pragma unroll
    for (int mt = 0; mt < 2; ++mt) {
        #pragma unroll
        for (int rg = 0; rg < 4; ++rg) {
            int ij = rt*32 + mt*16 + quad*4 + rg;
            int i = bi*8 + (ij >> 3), j = bj*8 + (ij & 7);
            float v = (acc2[mt][rg] + obv) * norm_inv[i*NDIM + j];
            out[((size_t)(i*NDIM + j))*OUTC + o] = v;
        }
    }
}

// ---------------------------------------------------------------------------
extern "C" void kernel_launch(void* const* d_in, const int* in_sizes, int n_in,
                              void* d_out, int out_size, void* d_ws, size_t ws_size,
                              hipStream_t stream) {
    const float* act  = (const float*)d_in[0];
    const float* mask = (const float*)d_in[1];
    const float* ln_g = (const float*)d_in[2];
    const float* ln_b = (const float*)d_in[3];
    const float* lw   = (const float*)d_in[4];
    const float* lb   = (const float*)d_in[5];
    const float* rw   = (const float*)d_in[6];
    const float* rb   = (const float*)d_in[7];
    const float* ow   = (const float*)d_in[8];
    const float* ob   = (const float*)d_in[9];
    float* out = (float*)d_out;

    unsigned char* ws = (unsigned char*)d_ws;
    __bf16* left_f   = (__bf16*)(ws + 0);                 // 2 MB
    __bf16* right_f  = (__bf16*)(ws + (2u<<20));          // 2 MB
    __bf16* owb_f    = (__bf16*)(ws + (4u<<20));          // 256 KB
    float*  norm_inv = (float*) (ws + (4u<<20) + (256u<<10));   // 256 KB
    __bf16* wb       = (__bf16*)(ws + (4u<<20) + (512u<<10));   // 32 KB
    float*  cbias    = (float*) (ws + (4u<<20) + (544u<<10));   // 256 B

    hipFuncSetAttribute((const void*)outer_kernel,
                        hipFuncAttributeMaxDynamicSharedMemorySize, LSX_BYTES);

    prep_kernel<<<328, 256, 0, stream>>>(mask, lw, lb, rw, rb, ow,
                                         wb, cbias, owb_f, norm_inv);
    ln_proj_kernel<<<dim3(256, 2), 256, 0, stream>>>(act, mask, ln_g, ln_b,
                                                     wb, cbias, left_f, right_f);
    outer_kernel<<<1024, 1024, LSX_BYTES, stream>>>(left_f, right_f, owb_f, ob,
                                                    norm_inv, out);
}

// Round 5
// 153.261 us; speedup vs baseline: 1.6774x; 1.0339x over previous
//
#include <hip/hip_runtime.h>
#include <hip/hip_bf16.h>

typedef __bf16 bf16x8 __attribute__((ext_vector_type(8)));
typedef __bf16 bf16x4 __attribute__((ext_vector_type(4)));
typedef float  f32x4  __attribute__((ext_vector_type(4)));
typedef float  f32x16 __attribute__((ext_vector_type(16)));

#define MDIM 128   // MSA rows (m)
#define NDIM 256   // residues (i/j)
#define CDIM 256   // channels
#define MIDC 32
#define OUTC 128

// lsX: [64 ij][k' = y*32+x mapped to y*36 + x], row stride 1156 bf16.
// RS/2 = 578 dw == 2 mod 32; relayout b64 writes verified 0-conflict (R2/R4).
#define LSX_RS 1156
#define LSX_YS 36
#define LSX_BYTES (64 * LSX_RS * 2)   // 147968 B

// ---------------------------------------------------------------------------
// prep: norm_inv, wb (lw||rw bf16), cbias, and owb_f packed for the 32x32x16
// B-operand: frag (ot in 0..3, s in 0..63):
//   owb_f[((ot*64+s)*64 + lane)*8 + j] = ow[o][x*32+y]
//   with o = ot*32 + (lane&31), x = (s&1)*16 + (lane>>5)*8 + j, y = s>>1.
// ---------------------------------------------------------------------------
__global__ __launch_bounds__(256) void prep_kernel(
    const float* __restrict__ mask,
    const float* __restrict__ lw, const float* __restrict__ lb,
    const float* __restrict__ rw, const float* __restrict__ rb,
    const float* __restrict__ ow,
    __bf16* __restrict__ wb, float* __restrict__ cbias,
    __bf16* __restrict__ owb_f, float* __restrict__ norm_inv)
{
    int b = blockIdx.x, t = threadIdx.x;
    if (b < 256) {
        float s = 0.f;
        #pragma unroll 8
        for (int m = 0; m < MDIM; ++m)
            s += mask[m*NDIM + b] * mask[m*NDIM + t];
        norm_inv[b*NDIM + t] = 1.0f / (s + 1e-3f);
    } else if (b < 320) {
        int e0 = (b - 256)*2048 + t*8;
        #pragma unroll
        for (int jj = 0; jj < 8; ++jj) {
            int e = e0 + jj;
            int lane = (e >> 3) & 63;
            int s = (e >> 9) & 63;
            int ot = e >> 15;
            int o = ot*32 + (lane & 31);
            int x = (s & 1)*16 + (lane >> 5)*8 + jj;
            int y = s >> 1;
            owb_f[e] = (__bf16)ow[o*1024 + x*32 + y];
        }
    } else {
        int e0 = (b - 320)*2048 + t*8;
        #pragma unroll
        for (int j = 0; j < 8; ++j) {
            int e = e0 + j;
            int row = e >> 8, c = e & 255;
            wb[e] = (__bf16)(row < MIDC ? lw[row*CDIM + c] : rw[(row - MIDC)*CDIM + c]);
        }
        if (b == 320 && t < 64) cbias[t] = (t < MIDC) ? lb[t] : rb[t - MIDC];
    }
}

// ---------------------------------------------------------------------------
// ln_proj: unchanged from R4 (LN -> MFMA -> transpose -> fragment-linear out)
// grid: dim3(256, 2) x 256
// ---------------------------------------------------------------------------
__global__ __launch_bounds__(256) void ln_proj_kernel(
    const float* __restrict__ act, const float* __restrict__ mask,
    const float* __restrict__ ln_g, const float* __restrict__ ln_b,
    const __bf16* __restrict__ wb, const float* __restrict__ cbias,
    __bf16* __restrict__ left_f, __bf16* __restrict__ right_f)
{
    __shared__ __bf16 xls[64][264];
    __shared__ __bf16 T[64][72];
    int t = threadIdx.x, lane = t & 63, w = t >> 6;
    int quad = lane >> 4, l16 = lane & 15;
    int b  = blockIdx.x;
    int m0 = blockIdx.y * 64;

    float4 gv = *(const float4*)(ln_g + lane*4);
    float4 bv = *(const float4*)(ln_b + lane*4);
    const float inv_c = 1.0f / 256.0f;

    #pragma unroll 4
    for (int s = 0; s < 16; ++s) {
        int m = m0 + w*16 + s;
        float4 v = *(const float4*)(act + ((size_t)m*NDIM + b)*CDIM + lane*4);
        float sum = v.x + v.y + v.z + v.w;
        float ssq = v.x*v.x + v.y*v.y + v.z*v.z + v.w*v.w;
        #pragma unroll
        for (int d = 1; d < 64; d <<= 1) {
            sum += __shfl_xor(sum, d);
            ssq += __shfl_xor(ssq, d);
        }
        float mu   = sum * inv_c;
        float var  = ssq * inv_c - mu*mu;
        float rstd = rsqrtf(var + 1e-5f);
        bf16x4 o;
        o.x = (__bf16)((v.x - mu)*rstd*gv.x + bv.x);
        o.y = (__bf16)((v.y - mu)*rstd*gv.y + bv.y);
        o.z = (__bf16)((v.z - mu)*rstd*gv.z + bv.z);
        o.w = (__bf16)((v.w - mu)*rstd*gv.w + bv.w);
        *(bf16x4*)&xls[w*16 + s][lane*4] = o;
    }

    f32x4 acc[4] = {};
    const __bf16* arow = &xls[w*16 + l16][0];
    #pragma unroll
    for (int k0 = 0; k0 < 256; k0 += 32) {
        bf16x8 a = *(const bf16x8*)(arow + k0 + quad*8);
        #pragma unroll
        for (int tt = 0; tt < 4; ++tt) {
            bf16x8 bb = *(const bf16x8*)(wb + (size_t)(tt*16 + l16)*CDIM + k0 + quad*8);
            acc[tt] = __builtin_amdgcn_mfma_f32_16x16x32_bf16(a, bb, acc[tt], 0, 0, 0);
        }
    }

    #pragma unroll
    for (int rg = 0; rg < 4; ++rg) {
        int ml = w*16 + quad*4 + rg;
        float mval = mask[(size_t)(m0 + ml)*NDIM + b];
        #pragma unroll
        for (int tt = 0; tt < 4; ++tt) {
            int o = tt*16 + l16;
            T[o][ml] = (__bf16)(mval * (acc[tt][rg] + cbias[o]));
        }
    }
    __syncthreads();

    {
        int fl16  = t & 15;
        int r     = t >> 4;
        int q     = r & 3;
        int k0loc = (r >> 2) & 1;
        int half  = (r >> 3) & 1;
        int tile  = b*2 + half;
        int k0    = (m0 >> 5) + k0loc;
        size_t dstoff = (((size_t)tile*4 + k0)*64 + q*16 + fl16)*8;
        #pragma unroll
        for (int side = 0; side < 2; ++side) {
            int o = side*32 + half*16 + fl16;
            bf16x8 d = *(const bf16x8*)&T[o][k0loc*32 + q*8];
            __bf16* dst = side ? right_f : left_f;
            *(bf16x8*)(dst + dstoff) = d;
        }
    }
}

// ---------------------------------------------------------------------------
// outer v5: 8i x 8j (64 ij), 1024 threads / 16 waves.
//   stage A+B (128 KB, uint4) -> b1
//   GEMM1 256x256x128 from LDS (16x16x32, wave grid 4x4) -> b2
//   relayout acc1 -> lsX[ij][y*36+x] (b64, 0-conflict) -> b3
//   GEMM2 64x128x1024 via 32x32x16; wave = (ot 0..3, kq 0..3); owb once -> b4
//   kq>0 waves dump partials to scratch -> b5; kq=0 reduce + epilogue.
// grid: 1024 blocks (XCD-swizzled)
// ---------------------------------------------------------------------------
__global__ __launch_bounds__(1024, 1) void outer_kernel(
    const __bf16* __restrict__ left_f, const __bf16* __restrict__ right_f,
    const __bf16* __restrict__ owb_f, const float* __restrict__ ob,
    const float* __restrict__ norm_inv, float* __restrict__ out)
{
    extern __shared__ __bf16 lsX[];
    int t = threadIdx.x, lane = t & 63, w = t >> 6;   // w 0..15
    int quad = lane >> 4, l16 = lane & 15;
    int l31 = lane & 31, half = lane >> 5;

    int id = blockIdx.x;
    int xcd = id & 7, p = id >> 3;
    int bi = xcd*4 + (p & 3);
    int bj = p >> 2;

    // ---- stage A (64 KB) + B (64 KB) into LDS, linear fragment order ----
    {
        uint4* ls4 = (uint4*)lsX;
        const uint4* gA4 = (const uint4*)(left_f  + (size_t)bi*32768);
        const uint4* gB4 = (const uint4*)(right_f + (size_t)bj*32768);
        #pragma unroll
        for (int r = 0; r < 4; ++r) ls4[r*1024 + t]        = gA4[r*1024 + t];
        #pragma unroll
        for (int r = 0; r < 4; ++r) ls4[4096 + r*1024 + t] = gB4[r*1024 + t];
    }
    __syncthreads();   // b1

    // ---- GEMM1: 256x256x128, wave (wr,wc) owns 64x64, frags from LDS ----
    int wr = w & 3, wc = w >> 2;
    const __bf16* lsA = lsX;
    const __bf16* lsB = lsX + 32768;

    f32x4 acc1[4][4] = {};
    #pragma unroll
    for (int kk = 0; kk < 4; ++kk) {
        bf16x8 af[4], bg[4];
        #pragma unroll
        for (int tr = 0; tr < 4; ++tr)
            af[tr] = *(const bf16x8*)(lsA + (size_t)(((wr*4 + tr)*4 + kk)*512) + lane*8);
        #pragma unroll
        for (int tc = 0; tc < 4; ++tc)
            bg[tc] = *(const bf16x8*)(lsB + (size_t)(((wc*4 + tc)*4 + kk)*512) + lane*8);
        #pragma unroll
        for (int tr = 0; tr < 4; ++tr)
            #pragma unroll
            for (int tc = 0; tc < 4; ++tc)
                acc1[tr][tc] = __builtin_amdgcn_mfma_f32_16x16x32_bf16(af[tr], bg[tc], acc1[tr][tc], 0, 0, 0);
    }

    // ---- GEMM2 setup + owb prefetch (L2 loads fly across the barriers) ----
    int ot = w & 3, kq = w >> 2;
    const __bf16* Ob = owb_f + ((size_t)(ot*64 + kq*16)*64 + lane)*8;
    bf16x8 bbuf0 = *(const bf16x8*)(Ob);
    bf16x8 bbuf1 = *(const bf16x8*)(Ob + 512);

    __syncthreads();   // b2: staging reads done; lsX region can be overwritten

    // ---- relayout: (i,x)x(j,y) -> lsX[il*8+jl][y*36 + x], b64 writes ----
    #pragma unroll
    for (int tr = 0; tr < 4; ++tr) {
        int il = wr*2 + (tr >> 1);
        int x0 = (tr & 1)*16 + quad*4;
        #pragma unroll
        for (int tc = 0; tc < 4; ++tc) {
            int jl = wc*2 + (tc >> 1);
            int y  = (tc & 1)*16 + l16;
            bf16x4 pk;
            pk.x = (__bf16)acc1[tr][tc][0];
            pk.y = (__bf16)acc1[tr][tc][1];
            pk.z = (__bf16)acc1[tr][tc][2];
            pk.w = (__bf16)acc1[tr][tc][3];
            *(bf16x4*)(lsX + (size_t)(il*8 + jl)*LSX_RS + y*LSX_YS + x0) = pk;
        }
    }
    __syncthreads();   // b3

    // ---- GEMM2: 32x32x16; wave (ot,kq): o-tile ot, k-steps kq*16..+16,
    //      both row-tiles (rt) per wave -> owb read exactly once per block ----
    f32x16 acc2[2] = {};
    const __bf16* Xb = lsX + (size_t)l31*LSX_RS + half*8;
    #pragma unroll 4
    for (int ss = 0; ss < 16; ++ss) {
        int s = kq*16 + ss;
        bf16x8 bb = bbuf0;
        bbuf0 = bbuf1;
        if (ss + 2 < 16) bbuf1 = *(const bf16x8*)(Ob + (ss + 2)*512);
        int xoff = (s >> 1)*LSX_YS + (s & 1)*16;
        #pragma unroll
        for (int rt = 0; rt < 2; ++rt) {
            const __bf16* ap = Xb + (size_t)rt*32*LSX_RS + xoff;
            bf16x4 lo = *(const bf16x4*)(ap);
            bf16x4 hi = *(const bf16x4*)(ap + 4);
            bf16x8 a  = __builtin_shufflevector(lo, hi, 0, 1, 2, 3, 4, 5, 6, 7);
            acc2[rt] = __builtin_amdgcn_mfma_f32_32x32x16_bf16(a, bb, acc2[rt], 0, 0, 0);
        }
    }

    __syncthreads();   // b4: all lsX reads done; scratch overlay safe

    // ---- K-quarter reduce: kq>0 dump to scratch [kq-1][ot*2+rt][row*32+col] ----
    float* scr = (float*)lsX;   // 3 * 8 * 1024 * 4 B = 96 KB
    if (kq > 0) {
        int base = (kq - 1)*8192 + ot*2048;
        #pragma unroll
        for (int rt = 0; rt < 2; ++rt) {
            #pragma unroll
            for (int r = 0; r < 16; ++r) {
                int row = (r & 3) + 8*(r >> 2) + 4*half;
                scr[base + rt*1024 + row*32 + l31] = acc2[rt][r];
            }
        }
    }
    __syncthreads();   // b5

    if (kq == 0) {
        int o = ot*32 + l31;
        float obv = ob[o];
        #pragma unroll
        for (int rt = 0; rt < 2; ++rt) {
            #pragma unroll
            for (int r = 0; r < 16; ++r) {
                int row = (r & 3) + 8*(r >> 2) + 4*half;
                int idx = ot*2048 + rt*1024 + row*32 + l31;
                float v = acc2[rt][r] + scr[idx] + scr[8192 + idx] + scr[16384 + idx];
                int ij = rt*32 + row;
                int i = bi*8 + (ij >> 3), j = bj*8 + (ij & 7);
                out[((size_t)(i*NDIM + j))*OUTC + o] = (v + obv) * norm_inv[i*NDIM + j];
            }
        }
    }
}

// ---------------------------------------------------------------------------
extern "C" void kernel_launch(void* const* d_in, const int* in_sizes, int n_in,
                              void* d_out, int out_size, void* d_ws, size_t ws_size,
                              hipStream_t stream) {
    const float* act  = (const float*)d_in[0];
    const float* mask = (const float*)d_in[1];
    const float* ln_g = (const float*)d_in[2];
    const float* ln_b = (const float*)d_in[3];
    const float* lw   = (const float*)d_in[4];
    const float* lb   = (const float*)d_in[5];
    const float* rw   = (const float*)d_in[6];
    const float* rb   = (const float*)d_in[7];
    const float* ow   = (const float*)d_in[8];
    const float* ob   = (const float*)d_in[9];
    float* out = (float*)d_out;

    unsigned char* ws = (unsigned char*)d_ws;
    __bf16* left_f   = (__bf16*)(ws + 0);                 // 2 MB
    __bf16* right_f  = (__bf16*)(ws + (2u<<20));          // 2 MB
    __bf16* owb_f    = (__bf16*)(ws + (4u<<20));          // 256 KB
    float*  norm_inv = (float*) (ws + (4u<<20) + (256u<<10));   // 256 KB
    __bf16* wb       = (__bf16*)(ws + (4u<<20) + (512u<<10));   // 32 KB
    float*  cbias    = (float*) (ws + (4u<<20) + (544u<<10));   // 256 B

    hipFuncSetAttribute((const void*)outer_kernel,
                        hipFuncAttributeMaxDynamicSharedMemorySize, LSX_BYTES);

    prep_kernel<<<328, 256, 0, stream>>>(mask, lw, lb, rw, rb, ow,
                                         wb, cbias, owb_f, norm_inv);
    ln_proj_kernel<<<dim3(256, 2), 256, 0, stream>>>(act, mask, ln_g, ln_b,
                                                     wb, cbias, left_f, right_f);
    outer_kernel<<<1024, 1024, LSX_BYTES, stream>>>(left_f, right_f, owb_f, ob,
                                                    norm_inv, out);
}